// Round 1
// baseline (845.066 us; speedup 1.0000x reference)
//
#include <hip/hip_runtime.h>

typedef unsigned short ushort_t;
typedef __attribute__((ext_vector_type(8))) short short8;
typedef __attribute__((ext_vector_type(4))) short short4v;
typedef __attribute__((ext_vector_type(4))) float f32x4;

__device__ __forceinline__ ushort_t f2bf(float f) {
    union { float f; unsigned int u; } c; c.f = f;
    unsigned int r = c.u + 0x7fffu + ((c.u >> 16) & 1u);  // RNE
    return (ushort_t)(r >> 16);
}

// ---------------------------------------------------------------------------
// Kernel 0: convert W1 (256x128) and W2 (128x64) fp32 -> bf16 in MFMA
// B-fragment order. Fragment (kt, nt): lane l holds W[k][n] for
// n = nt*16 + (l&15), k = kt*32 + (l>>4)*8 + j, j=0..7 (contiguous 16B).
// W1f: 64 frags (nt 0..7, kt 0..7) -> 32768 ushorts. W2f: 16 frags -> 8192.
// ---------------------------------------------------------------------------
__global__ __launch_bounds__(256) void build_wfrags(
    const float* __restrict__ W1, const float* __restrict__ W2,
    ushort_t* __restrict__ W1f, ushort_t* __restrict__ W2f)
{
    int tid = blockIdx.x * 256 + threadIdx.x;
    if (tid < 32768) {
        int j = tid & 7, l = (tid >> 3) & 63, fi = tid >> 9; // fi = nt*8+kt
        int nt = fi >> 3, kt = fi & 7;
        int n = nt * 16 + (l & 15);
        int k = kt * 32 + (l >> 4) * 8 + j;
        W1f[tid] = f2bf(W1[k * 128 + n]);
    } else if (tid < 40960) {
        int u = tid - 32768;
        int j = u & 7, l = (u >> 3) & 63, fi = u >> 9;      // fi = nt*4+kt
        int nt = fi >> 2, kt = fi & 3;
        int n = nt * 16 + (l & 15);
        int k = kt * 32 + (l >> 4) * 8 + j;
        W2f[u] = f2bf(W2[k * 64 + n]);
    }
}

// ---------------------------------------------------------------------------
// Kernel 1: per-row MLP logits. 256 threads = 4 waves. Each block handles
// 4 subtiles of 16 rows (64 rows). Waves split the N dimension:
//   L1 (256->128): wave w owns N-tiles {2w, 2w+1} -> 16 MFMA/wave/subtile
//   L2 (128->64):  wave w owns N-tile w           -> 4 MFMA/wave/subtile
//   L3 (64->1):    per-lane products + quad shuffle reduce
// W fragments live in VGPRs, loaded once per block (L2-hot).
// ---------------------------------------------------------------------------
#define TPB 4

__global__ __launch_bounds__(256) void mlp_logits(
    const float* __restrict__ X, const ushort_t* __restrict__ W1f,
    const ushort_t* __restrict__ W2f, const float* __restrict__ b1,
    const float* __restrict__ b2, const float* __restrict__ W3,
    const float* __restrict__ b3, float* __restrict__ logits)
{
    __shared__ ushort_t xs[16 * 264];   // 16 rows x 256 bf16, stride 264 (pad)
    __shared__ ushort_t h1s[16 * 136];  // 16 rows x 128 bf16, stride 136 (pad)
    __shared__ float part[4][16];

    const int t = threadIdx.x;
    const int w = t >> 6, lane = t & 63;
    const int q = lane >> 4, c16 = lane & 15;

    // Preload weight fragments into VGPRs (reused across 4 subtiles)
    short8 w1f[2][8];
    for (int i = 0; i < 2; ++i) {
        int nt = 2 * w + i;
        for (int kt = 0; kt < 8; ++kt)
            w1f[i][kt] = ((const short8*)W1f)[(nt * 8 + kt) * 64 + lane];
    }
    short8 w2f[4];
    for (int kt = 0; kt < 4; ++kt)
        w2f[kt] = ((const short8*)W2f)[(w * 4 + kt) * 64 + lane];
    float bias1[2];
    bias1[0] = b1[(2 * w) * 16 + c16];
    bias1[1] = b1[(2 * w + 1) * 16 + c16];
    const float bias2 = b2[w * 16 + c16];
    const float w3v = W3[w * 16 + c16];
    const float b3v = b3[0];

    const int rowb0 = blockIdx.x * (16 * TPB);

    for (int sub = 0; sub < TPB; ++sub) {
        const int rowb = rowb0 + sub * 16;

        // stage 16 rows of X into LDS as bf16 (coalesced 1KB/row loads)
        for (int i = 0; i < 4; ++i) {
            int r = i * 4 + w;
            const f32x4 v = *(const f32x4*)(X + (size_t)(rowb + r) * 256 + lane * 4);
            short4v h;
            h[0] = (short)f2bf(v[0]); h[1] = (short)f2bf(v[1]);
            h[2] = (short)f2bf(v[2]); h[3] = (short)f2bf(v[3]);
            *(short4v*)(xs + r * 264 + lane * 4) = h;
        }
        __syncthreads();

        // Layer 1: [16x256] @ [256x128]
        f32x4 acc0 = {0.f, 0.f, 0.f, 0.f}, acc1 = {0.f, 0.f, 0.f, 0.f};
        for (int kt = 0; kt < 8; ++kt) {
            short8 a = *(const short8*)(xs + c16 * 264 + kt * 32 + q * 8);
            acc0 = __builtin_amdgcn_mfma_f32_16x16x32_bf16(a, w1f[0][kt], acc0, 0, 0, 0);
            acc1 = __builtin_amdgcn_mfma_f32_16x16x32_bf16(a, w1f[1][kt], acc1, 0, 0, 0);
        }
        // bias + relu, write h1 to LDS (row-major [16][128] bf16)
        for (int i = 0; i < 2; ++i) {
            f32x4 a = i ? acc1 : acc0;
            int col = (2 * w + i) * 16 + c16;
            for (int reg = 0; reg < 4; ++reg) {
                float v = fmaxf(a[reg] + bias1[i], 0.f);
                h1s[(q * 4 + reg) * 136 + col] = f2bf(v);
            }
        }
        __syncthreads();

        // Layer 2: [16x128] @ [128x64]
        f32x4 acc2 = {0.f, 0.f, 0.f, 0.f};
        for (int kt = 0; kt < 4; ++kt) {
            short8 a = *(const short8*)(h1s + c16 * 136 + kt * 32 + q * 8);
            acc2 = __builtin_amdgcn_mfma_f32_16x16x32_bf16(a, w2f[kt], acc2, 0, 0, 0);
        }
        // Layer 3: relu then dot with W3 column slice; reduce over 16 lanes/quad
        float p[4];
        for (int reg = 0; reg < 4; ++reg)
            p[reg] = fmaxf(acc2[reg] + bias2, 0.f) * w3v;
        for (int m = 1; m < 16; m <<= 1)
            for (int reg = 0; reg < 4; ++reg)
                p[reg] += __shfl_xor(p[reg], m);
        if (c16 == 0)
            for (int reg = 0; reg < 4; ++reg)
                part[w][q * 4 + reg] = p[reg];
        __syncthreads();
        if (t < 16)
            logits[rowb + t] = part[0][t] + part[1][t] + part[2][t] + part[3][t] + b3v;
        // next subtile's staging is guarded by this iteration's last barrier +
        // the next iteration's first barrier
    }
}

// ---------------------------------------------------------------------------
// Kernel 2: per-graph softmax + weighted pooling. One block per graph.
// Indices are sorted -> binary search row range. Thread d owns output dim d.
// ---------------------------------------------------------------------------
__global__ __launch_bounds__(256) void pool(
    const float* __restrict__ X, const int* __restrict__ idx,
    const float* __restrict__ logits, float* __restrict__ out, int nrows)
{
    const int g = blockIdx.x;
    const int t = threadIdx.x;
    const int w = t >> 6, lane = t & 63;

    // lower_bound(idx, g) and lower_bound(idx, g+1)
    int lo = 0, hi = nrows;
    while (lo < hi) { int mid = (lo + hi) >> 1; if (idx[mid] < g) lo = mid + 1; else hi = mid; }
    const int start = lo;
    hi = nrows;
    while (lo < hi) { int mid = (lo + hi) >> 1; if (idx[mid] < g + 1) lo = mid + 1; else hi = mid; }
    const int cnt = lo - start;

    __shared__ float red[4];
    __shared__ float att[256];

    // segment max
    float m = -3.0e38f;
    for (int i = t; i < cnt; i += 256) m = fmaxf(m, logits[start + i]);
    for (int o = 32; o; o >>= 1) m = fmaxf(m, __shfl_down(m, o));
    if (lane == 0) red[w] = m;
    __syncthreads();
    m = fmaxf(fmaxf(red[0], red[1]), fmaxf(red[2], red[3]));
    __syncthreads();

    // segment exp-sum
    float s = 0.f;
    for (int i = t; i < cnt; i += 256) s += __expf(logits[start + i] - m);
    for (int o = 32; o; o >>= 1) s += __shfl_down(s, o);
    if (lane == 0) red[w] = s;
    __syncthreads();
    s = red[0] + red[1] + red[2] + red[3];
    const float inv = (cnt > 0) ? 1.f / s : 0.f;

    // weighted accumulation: thread t owns dim t
    float acc = 0.f;
    for (int base = 0; base < cnt; base += 256) {
        const int c = min(256, cnt - base);
        __syncthreads();
        if (t < c) att[t] = __expf(logits[start + base + t] - m) * inv;
        __syncthreads();
        const float* xp = X + (size_t)(start + base) * 256 + t;
        int r = 0;
        for (; r + 4 <= c; r += 4) {
            float a0 = att[r], a1 = att[r + 1], a2 = att[r + 2], a3 = att[r + 3];
            acc += a0 * xp[(size_t)(r + 0) * 256] + a1 * xp[(size_t)(r + 1) * 256]
                 + a2 * xp[(size_t)(r + 2) * 256] + a3 * xp[(size_t)(r + 3) * 256];
        }
        for (; r < c; ++r) acc += att[r] * xp[(size_t)r * 256];
    }
    out[(size_t)g * 256 + t] = acc;
}

// ---------------------------------------------------------------------------

extern "C" void kernel_launch(void* const* d_in, const int* in_sizes, int n_in,
                              void* d_out, int out_size, void* d_ws, size_t ws_size,
                              hipStream_t stream) {
    const float* Xn  = (const float*)d_in[0];
    const float* Xe  = (const float*)d_in[1];
    const int* idxn  = (const int*)d_in[2];
    const int* idxe  = (const int*)d_in[3];
    const float* Wn1 = (const float*)d_in[4];
    const float* bn1 = (const float*)d_in[5];
    const float* Wn2 = (const float*)d_in[6];
    const float* bn2 = (const float*)d_in[7];
    const float* Wn3 = (const float*)d_in[8];
    const float* bn3 = (const float*)d_in[9];
    const float* We1 = (const float*)d_in[10];
    const float* be1 = (const float*)d_in[11];
    const float* We2 = (const float*)d_in[12];
    const float* be2 = (const float*)d_in[13];
    const float* We3 = (const float*)d_in[14];
    const float* be3 = (const float*)d_in[15];
    float* out = (float*)d_out;

    char* ws = (char*)d_ws;
    ushort_t* W1f_n = (ushort_t*)(ws + 0);        // 65536 B
    ushort_t* W2f_n = (ushort_t*)(ws + 65536);    // 16384 B
    ushort_t* W1f_e = (ushort_t*)(ws + 81920);    // 65536 B
    ushort_t* W2f_e = (ushort_t*)(ws + 147456);   // 16384 B
    float* log_n = (float*)(ws + 163840);         // 200000*4 = 800000 B
    float* log_e = (float*)(ws + 963840);         // 400000*4 B

    build_wfrags<<<160, 256, 0, stream>>>(Wn1, Wn2, W1f_n, W2f_n);
    build_wfrags<<<160, 256, 0, stream>>>(We1, We2, W1f_e, W2f_e);

    mlp_logits<<<200000 / (16 * TPB), 256, 0, stream>>>(Xn, W1f_n, W2f_n, bn1, bn2, Wn3, bn3, log_n);
    mlp_logits<<<400000 / (16 * TPB), 256, 0, stream>>>(Xe, W1f_e, W2f_e, be1, be2, We3, be3, log_e);

    pool<<<2048, 256, 0, stream>>>(Xn, idxn, log_n, out, 200000);
    pool<<<2048, 256, 0, stream>>>(Xe, idxe, log_e, out + (size_t)2048 * 256, 400000);
}

// Round 2
// 844.695 us; speedup vs baseline: 1.0004x; 1.0004x over previous
//
#include <hip/hip_runtime.h>

typedef unsigned short ushort_t;
typedef __attribute__((ext_vector_type(8))) short short8;
typedef __attribute__((ext_vector_type(4))) float f32x4;

__device__ __forceinline__ ushort_t f2bf(float f) {
    union { float f; unsigned int u; } c; c.f = f;
    unsigned int r = c.u + 0x7fffu + ((c.u >> 16) & 1u);  // RNE
    return (ushort_t)(r >> 16);
}

// ---------------------------------------------------------------------------
// Kernel 0: convert W1 (256x128) and W2 (128x64) fp32 -> bf16 in MFMA
// B-fragment order. Fragment (nt,kt): lane l holds W[k][n] for
// n = nt*16 + (l&15), k = kt*32 + (l>>4)*8 + j, j=0..7 (contiguous 16B).
// ---------------------------------------------------------------------------
__global__ __launch_bounds__(256) void build_wfrags(
    const float* __restrict__ W1, const float* __restrict__ W2,
    ushort_t* __restrict__ W1f, ushort_t* __restrict__ W2f)
{
    int tid = blockIdx.x * 256 + threadIdx.x;
    if (tid < 32768) {
        int j = tid & 7, l = (tid >> 3) & 63, fi = tid >> 9; // fi = nt*8+kt
        int nt = fi >> 3, kt = fi & 7;
        int n = nt * 16 + (l & 15);
        int k = kt * 32 + (l >> 4) * 8 + j;
        W1f[tid] = f2bf(W1[k * 128 + n]);
    } else if (tid < 40960) {
        int u = tid - 32768;
        int j = u & 7, l = (u >> 3) & 63, fi = u >> 9;      // fi = nt*4+kt
        int nt = fi >> 2, kt = fi & 3;
        int n = nt * 16 + (l & 15);
        int k = kt * 32 + (l >> 4) * 8 + j;
        W2f[u] = f2bf(W2[k * 64 + n]);
    }
}

// ---------------------------------------------------------------------------
// Kernel 1: per-row MLP logits — BARRIER-FREE hot path.
// Block = 8 waves, W1f+W2f staged to LDS once (one __syncthreads), then each
// wave independently processes MLP_TPW subtiles of 16 rows:
//   A-fragments loaded straight from global (16 dwordx4 issued up front,
//   16 KB in flight per wave), L1 = 64 MFMA (8 nt x 8 kt), h1 transposed
//   C->A layout through a WAVE-PRIVATE LDS scratch (no barrier: same-wave
//   ds ordering), L2 = 16 MFMA, L3 via quad shuffle reduce.
// ---------------------------------------------------------------------------
#define MLP_WAVES 8
#define MLP_TPW 2
#define MLP_LDS_BYTES (65536 + 16384 + MLP_WAVES * 16 * 136 * 2)  // 116736

__global__ __launch_bounds__(512) void mlp_logits(
    const float* __restrict__ X, const ushort_t* __restrict__ W1f,
    const ushort_t* __restrict__ W2f, const float* __restrict__ b1,
    const float* __restrict__ b2, const float* __restrict__ W3,
    const float* __restrict__ b3, float* __restrict__ logits, int nsub)
{
    extern __shared__ __align__(16) char smem[];
    ushort_t* W1s    = (ushort_t*)smem;             // 65536 B (64 frags)
    ushort_t* W2s    = (ushort_t*)(smem + 65536);   // 16384 B (16 frags)
    ushort_t* h1base = (ushort_t*)(smem + 81920);   // 8 waves * 4352 B

    const int t = threadIdx.x;
    const int w = t >> 6, lane = t & 63;
    const int q = lane >> 4, c16 = lane & 15;

    // cooperative W stage (L2-hot, once per block)
    {
        const f32x4* s1 = (const f32x4*)W1f; f32x4* d1 = (f32x4*)W1s;
        for (int i = t; i < 4096; i += 512) d1[i] = s1[i];
        const f32x4* s2 = (const f32x4*)W2f; f32x4* d2 = (f32x4*)W2s;
        for (int i = t; i < 1024; i += 512) d2[i] = s2[i];
    }
    __syncthreads();

    float bias1[8], bias2[4], w3v[4];
    #pragma unroll
    for (int nt = 0; nt < 8; ++nt) bias1[nt] = b1[nt * 16 + c16];
    #pragma unroll
    for (int nt = 0; nt < 4; ++nt) bias2[nt] = b2[nt * 16 + c16];
    #pragma unroll
    for (int nt = 0; nt < 4; ++nt) w3v[nt] = W3[nt * 16 + c16];
    const float b3v = b3[0];

    ushort_t* hw = h1base + w * (16 * 136);   // wave-private scratch

    for (int sub = 0; sub < MLP_TPW; ++sub) {
        const int s = (blockIdx.x * MLP_WAVES + w) * MLP_TPW + sub;
        if (s >= nsub) break;
        const float* xp = X + (size_t)(s * 16 + c16) * 256 + q * 8;

        // issue all 16 loads (256 B/lane) before any use
        f32x4 xv[16];
        #pragma unroll
        for (int kt = 0; kt < 8; ++kt) {
            xv[2 * kt]     = *(const f32x4*)(xp + kt * 32);
            xv[2 * kt + 1] = *(const f32x4*)(xp + kt * 32 + 4);
        }

        // Layer 1: [16x256] @ [256x128]
        f32x4 acc[8];
        #pragma unroll
        for (int nt = 0; nt < 8; ++nt) acc[nt] = (f32x4){0.f, 0.f, 0.f, 0.f};
        #pragma unroll
        for (int kt = 0; kt < 8; ++kt) {
            short8 a;
            #pragma unroll
            for (int j = 0; j < 4; ++j) {
                a[j]     = (short)f2bf(xv[2 * kt][j]);
                a[4 + j] = (short)f2bf(xv[2 * kt + 1][j]);
            }
            #pragma unroll
            for (int nt = 0; nt < 8; ++nt) {
                short8 bf = *(const short8*)(W1s + ((nt * 8 + kt) * 64 + lane) * 8);
                acc[nt] = __builtin_amdgcn_mfma_f32_16x16x32_bf16(a, bf, acc[nt], 0, 0, 0);
            }
        }

        // bias+relu, C-layout -> row-major bf16 in wave-private LDS
        #pragma unroll
        for (int nt = 0; nt < 8; ++nt)
            #pragma unroll
            for (int reg = 0; reg < 4; ++reg)
                hw[(q * 4 + reg) * 136 + nt * 16 + c16] =
                    f2bf(fmaxf(acc[nt][reg] + bias1[nt], 0.f));

        // Layer 2: [16x128] @ [128x64]  (same-wave ds_write->ds_read, no barrier)
        f32x4 acc2[4];
        #pragma unroll
        for (int nt = 0; nt < 4; ++nt) acc2[nt] = (f32x4){0.f, 0.f, 0.f, 0.f};
        #pragma unroll
        for (int kt = 0; kt < 4; ++kt) {
            short8 a = *(const short8*)(hw + c16 * 136 + kt * 32 + q * 8);
            #pragma unroll
            for (int nt = 0; nt < 4; ++nt) {
                short8 bf = *(const short8*)(W2s + ((nt * 4 + kt) * 64 + lane) * 8);
                acc2[nt] = __builtin_amdgcn_mfma_f32_16x16x32_bf16(a, bf, acc2[nt], 0, 0, 0);
            }
        }

        // Layer 3: relu, dot with W3, reduce over 16 lanes per quad
        float p[4];
        #pragma unroll
        for (int reg = 0; reg < 4; ++reg) {
            float v = 0.f;
            #pragma unroll
            for (int nt = 0; nt < 4; ++nt)
                v += fmaxf(acc2[nt][reg] + bias2[nt], 0.f) * w3v[nt];
            p[reg] = v;
        }
        #pragma unroll
        for (int msk = 1; msk < 16; msk <<= 1)
            #pragma unroll
            for (int reg = 0; reg < 4; ++reg)
                p[reg] += __shfl_xor(p[reg], msk);
        if (c16 == 0) {
            #pragma unroll
            for (int reg = 0; reg < 4; ++reg)
                logits[s * 16 + q * 4 + reg] = p[reg] + b3v;
        }
    }
}

// ---------------------------------------------------------------------------
// Kernel 2: per-graph softmax + weighted pooling. One block (4 waves) per
// graph. Lane owns 4 dims (float4 loads, 16 B/lane); waves stride rows by 4;
// unroll-4 keeps 64 B/lane in flight. inv multiply deferred to epilogue.
// ---------------------------------------------------------------------------
__global__ __launch_bounds__(256) void pool(
    const float* __restrict__ X, const int* __restrict__ idx,
    const float* __restrict__ logits, float* __restrict__ out, int nrows)
{
    const int g = blockIdx.x;
    const int t = threadIdx.x;
    const int w = t >> 6, lane = t & 63;

    int lo = 0, hi = nrows;
    while (lo < hi) { int mid = (lo + hi) >> 1; if (idx[mid] < g) lo = mid + 1; else hi = mid; }
    const int start = lo;
    hi = nrows;
    while (lo < hi) { int mid = (lo + hi) >> 1; if (idx[mid] < g + 1) lo = mid + 1; else hi = mid; }
    const int cnt = lo - start;

    __shared__ float red[8];
    __shared__ float parts[4][256];

    const float* lg = logits + start;

    // segment max
    float m = -3.0e38f;
    for (int i = t; i < cnt; i += 256) m = fmaxf(m, lg[i]);
    #pragma unroll
    for (int o = 32; o; o >>= 1) m = fmaxf(m, __shfl_xor(m, o));
    if (lane == 0) red[w] = m;
    __syncthreads();
    m = fmaxf(fmaxf(red[0], red[1]), fmaxf(red[2], red[3]));

    // segment exp-sum
    float ssum = 0.f;
    for (int i = t; i < cnt; i += 256) ssum += __expf(lg[i] - m);
    #pragma unroll
    for (int o = 32; o; o >>= 1) ssum += __shfl_xor(ssum, o);
    if (lane == 0) red[4 + w] = ssum;
    __syncthreads();
    ssum = red[4] + red[5] + red[6] + red[7];
    const float inv = (cnt > 0) ? 1.f / ssum : 0.f;

    // weighted accumulation: wave w rows {w, w+4, ...}, lane dims lane*4..+3
    f32x4 acc = {0.f, 0.f, 0.f, 0.f};
    const float* xb = X + (size_t)start * 256 + lane * 4;
    int r = w;
    for (; r + 12 < cnt; r += 16) {
        float a0 = __expf(lg[r] - m);
        float a1 = __expf(lg[r + 4] - m);
        float a2 = __expf(lg[r + 8] - m);
        float a3 = __expf(lg[r + 12] - m);
        f32x4 x0 = *(const f32x4*)(xb + (size_t)(r) * 256);
        f32x4 x1 = *(const f32x4*)(xb + (size_t)(r + 4) * 256);
        f32x4 x2 = *(const f32x4*)(xb + (size_t)(r + 8) * 256);
        f32x4 x3 = *(const f32x4*)(xb + (size_t)(r + 12) * 256);
        acc += a0 * x0;
        acc += a1 * x1;
        acc += a2 * x2;
        acc += a3 * x3;
    }
    for (; r < cnt; r += 4) {
        float a = __expf(lg[r] - m);
        f32x4 xv = *(const f32x4*)(xb + (size_t)r * 256);
        acc += a * xv;
    }
    #pragma unroll
    for (int j = 0; j < 4; ++j) parts[w][lane * 4 + j] = acc[j] * inv;
    __syncthreads();
    out[(size_t)g * 256 + t] = parts[0][t] + parts[1][t] + parts[2][t] + parts[3][t];
}

// ---------------------------------------------------------------------------

extern "C" void kernel_launch(void* const* d_in, const int* in_sizes, int n_in,
                              void* d_out, int out_size, void* d_ws, size_t ws_size,
                              hipStream_t stream) {
    const float* Xn  = (const float*)d_in[0];
    const float* Xe  = (const float*)d_in[1];
    const int* idxn  = (const int*)d_in[2];
    const int* idxe  = (const int*)d_in[3];
    const float* Wn1 = (const float*)d_in[4];
    const float* bn1 = (const float*)d_in[5];
    const float* Wn2 = (const float*)d_in[6];
    const float* bn2 = (const float*)d_in[7];
    const float* Wn3 = (const float*)d_in[8];
    const float* bn3 = (const float*)d_in[9];
    const float* We1 = (const float*)d_in[10];
    const float* be1 = (const float*)d_in[11];
    const float* We2 = (const float*)d_in[12];
    const float* be2 = (const float*)d_in[13];
    const float* We3 = (const float*)d_in[14];
    const float* be3 = (const float*)d_in[15];
    float* out = (float*)d_out;

    char* ws = (char*)d_ws;
    ushort_t* W1f_n = (ushort_t*)(ws + 0);        // 65536 B
    ushort_t* W2f_n = (ushort_t*)(ws + 65536);    // 16384 B
    ushort_t* W1f_e = (ushort_t*)(ws + 81920);    // 65536 B
    ushort_t* W2f_e = (ushort_t*)(ws + 147456);   // 16384 B
    float* log_n = (float*)(ws + 163840);         // 200000*4 B
    float* log_e = (float*)(ws + 963840);         // 400000*4 B

    // allow >64KB dynamic LDS (gfx950 has 160 KiB/CU); idempotent, capture-safe
    (void)hipFuncSetAttribute((const void*)mlp_logits,
                              hipFuncAttributeMaxDynamicSharedMemorySize,
                              MLP_LDS_BYTES);

    build_wfrags<<<160, 256, 0, stream>>>(Wn1, Wn2, W1f_n, W2f_n);
    build_wfrags<<<160, 256, 0, stream>>>(We1, We2, W1f_e, W2f_e);

    // nodes fully, then pool while X_n (204.8 MB < 256 MiB L3) is cache-hot
    const int nsub_n = 200000 / 16, nsub_e = 400000 / 16;
    const int gpb = MLP_WAVES * MLP_TPW;  // subtiles per block
    mlp_logits<<<(nsub_n + gpb - 1) / gpb, 512, MLP_LDS_BYTES, stream>>>(
        Xn, W1f_n, W2f_n, bn1, bn2, Wn3, bn3, log_n, nsub_n);
    pool<<<2048, 256, 0, stream>>>(Xn, idxn, log_n, out, 200000);

    mlp_logits<<<(nsub_e + gpb - 1) / gpb, 512, MLP_LDS_BYTES, stream>>>(
        Xe, W1f_e, W2f_e, be1, be2, We3, be3, log_e, nsub_e);
    pool<<<2048, 256, 0, stream>>>(Xe, idxe, log_e, out + (size_t)2048 * 256, 400000);
}